// Round 1
// baseline (583.444 us; speedup 1.0000x reference)
//
#include <hip/hip_runtime.h>

#define N_NODES 203
#define NPC 29            // nodes per client = K of the matmul
#define BATCH 2048
#define ODIM 256
#define ROWLEN (BATCH * ODIM)   // 524288, inputs row stride

// Kernel 1: compute col[n][k] = dinv[n] * (adj[n][j] + (n==j)) * dinv[j],
// j = id*NPC + k. Single block, trivial cost (~few us).
__global__ __launch_bounds__(256) void lap_col_kernel(
    const float* __restrict__ adj, const int* __restrict__ idp,
    float* __restrict__ col) {
    __shared__ float dinv[N_NODES];
    const int t = threadIdx.x;
    if (t < N_NODES) {
        float s = 1.0f;  // self-loop contributes +1 to the row sum
        for (int j = 0; j < N_NODES; ++j) s += adj[t * N_NODES + j];
        dinv[t] = 1.0f / sqrtf(s);
    }
    __syncthreads();
    const int base = (*idp) * NPC;
    for (int idx = t; idx < N_NODES * NPC; idx += 256) {
        const int i = idx / NPC;
        const int k = idx - i * NPC;
        const int j = base + k;
        float a = adj[i * N_NODES + j] + (i == j ? 1.0f : 0.0f);
        col[idx] = dinv[i] * a * dinv[j];
    }
}

// Kernel 2: out[b][n][d] = sum_k col[n][k] * X[k][b*ODIM+d]
// Thread owns one float4 of j = b*ODIM+d. All 29 X values in registers,
// col staged in LDS (broadcast reads), 203 coalesced float4 stores.
__global__ __launch_bounds__(256) void gcn_mm_kernel(
    const float* __restrict__ X, const float* __restrict__ col,
    float* __restrict__ out) {
    __shared__ float cl[N_NODES * NPC];  // 23548 B
    for (int i = threadIdx.x; i < N_NODES * NPC; i += 256) cl[i] = col[i];
    __syncthreads();

    const int j0 = (blockIdx.x * 256 + threadIdx.x) * 4;  // < 524288
    float4 x[NPC];
#pragma unroll
    for (int k = 0; k < NPC; ++k)
        x[k] = *(const float4*)(X + (size_t)k * ROWLEN + j0);

    const int b = j0 >> 8;        // j0 / ODIM
    const int d = j0 & (ODIM - 1);
    float* obase = out + (size_t)b * (N_NODES * ODIM) + d;

    for (int n = 0; n < N_NODES; ++n) {
        float4 acc = {0.f, 0.f, 0.f, 0.f};
        const float* cn = &cl[n * NPC];
#pragma unroll
        for (int k = 0; k < NPC; ++k) {
            const float c = cn[k];
            acc.x += c * x[k].x;
            acc.y += c * x[k].y;
            acc.z += c * x[k].z;
            acc.w += c * x[k].w;
        }
        *(float4*)(obase + n * ODIM) = acc;
    }
}

extern "C" void kernel_launch(void* const* d_in, const int* in_sizes, int n_in,
                              void* d_out, int out_size, void* d_ws, size_t ws_size,
                              hipStream_t stream) {
    const float* adj = (const float*)d_in[0];   // (203, 203)
    const float* X   = (const float*)d_in[1];   // (29, 524288)
    const int*   idp = (const int*)d_in[4];     // scalar id
    float* out = (float*)d_out;                 // (2048, 203, 256)
    float* col = (float*)d_ws;                  // 203*29 floats scratch

    lap_col_kernel<<<1, 256, 0, stream>>>(adj, idp, col);

    const int total_j = ROWLEN;                  // 524288
    const int blocks = total_j / (256 * 4);      // 512
    gcn_mm_kernel<<<blocks, 256, 0, stream>>>(X, col, out);
}

// Round 4
// 576.198 us; speedup vs baseline: 1.0126x; 1.0126x over previous
//
#include <hip/hip_runtime.h>

#define N_NODES 203
#define NPC 29            // nodes per client = K of the matmul
#define BATCH 2048
#define ODIM 256
#define ROWLEN (BATCH * ODIM)   // 524288
#define NSPLIT 2
#define NCHUNK 102              // ceil(203/2)

typedef float v2f __attribute__((ext_vector_type(2)));

// Kernel 1: col[n][k] = dinv[n] * (adj[n][j] + (n==j)) * dinv[j], j = id*NPC+k
__global__ __launch_bounds__(256) void lap_col_kernel(
    const float* __restrict__ adj, const int* __restrict__ idp,
    float* __restrict__ col) {
    __shared__ float dinv[N_NODES];
    const int wid = threadIdx.x >> 6, lane = threadIdx.x & 63;
    // wave-parallel coalesced row sums
    for (int r = wid; r < N_NODES; r += 4) {
        float s = (lane == 0) ? 1.0f : 0.0f;   // self-loop +1
        for (int j = lane; j < N_NODES; j += 64) s += adj[r * N_NODES + j];
#pragma unroll
        for (int off = 32; off; off >>= 1) s += __shfl_down(s, off);
        if (lane == 0) dinv[r] = 1.0f / sqrtf(s);
    }
    __syncthreads();
    const int base = (*idp) * NPC;
    for (int idx = threadIdx.x; idx < N_NODES * NPC; idx += 256) {
        const int i = idx / NPC;
        const int k = idx - i * NPC;
        const int j = base + k;
        float a = adj[i * N_NODES + j] + (i == j ? 1.0f : 0.0f);
        col[idx] = dinv[i] * a * dinv[j];
    }
}

// Kernel 2: out[b][n][d] = sum_k col[n][k] * X[k][b*ODIM+d]
// Thread owns one float2 of j = b*ODIM+d (58 VGPRs of X state -> stays
// below the 128-VGPR occupancy cliff). Each block handles one n-chunk.
__global__ __launch_bounds__(256) void gcn_mm_kernel(
    const float* __restrict__ X, const float* __restrict__ col,
    float* __restrict__ out) {
    const int n0 = blockIdx.y * NCHUNK;
    const int n1 = (n0 + NCHUNK < N_NODES) ? (n0 + NCHUNK) : N_NODES;
    const int nn = n1 - n0;

    __shared__ float cl[NCHUNK * NPC];
    for (int i = threadIdx.x; i < nn * NPC; i += 256)
        cl[i] = col[n0 * NPC + i];
    __syncthreads();

    const int j0 = (blockIdx.x * 256 + threadIdx.x) * 2;
    v2f x[NPC];
#pragma unroll
    for (int k = 0; k < NPC; ++k)
        x[k] = *(const v2f*)(X + (size_t)k * ROWLEN + j0);

    const int b = j0 >> 8;          // j0 / ODIM
    const int d = j0 & (ODIM - 1);
    float* obase = out + (size_t)b * (N_NODES * ODIM) + d;

    for (int n = n0; n < n1; ++n) {
        v2f acc = {0.f, 0.f};
        const float* cn = &cl[(n - n0) * NPC];
#pragma unroll
        for (int k = 0; k < NPC; ++k) {
            const float c = cn[k];
            acc.x = fmaf(c, x[k].x, acc.x);
            acc.y = fmaf(c, x[k].y, acc.y);
        }
        __builtin_nontemporal_store(acc, (v2f*)(obase + (size_t)n * ODIM));
    }
}

extern "C" void kernel_launch(void* const* d_in, const int* in_sizes, int n_in,
                              void* d_out, int out_size, void* d_ws, size_t ws_size,
                              hipStream_t stream) {
    const float* adj = (const float*)d_in[0];   // (203, 203)
    const float* X   = (const float*)d_in[1];   // (29, 524288)
    const int*   idp = (const int*)d_in[4];     // scalar id
    float* out = (float*)d_out;                 // (2048, 203, 256)
    float* col = (float*)d_ws;                  // 203*29 floats scratch

    lap_col_kernel<<<1, 256, 0, stream>>>(adj, idp, col);

    dim3 grid(ROWLEN / (256 * 2), NSPLIT);      // (1024, 2)
    gcn_mm_kernel<<<grid, 256, 0, stream>>>(X, col, out);
}

// Round 6
// 480.286 us; speedup vs baseline: 1.2148x; 1.1997x over previous
//
#include <hip/hip_runtime.h>

#define N_NODES 203
#define NPC 29            // nodes per client = K of the matmul
#define ODIM 256
#define ROWLEN (2048 * ODIM)    // 524288
#define NSPLIT 2
#define NCHUNK 102              // ceil(203/2)

typedef float v2f __attribute__((ext_vector_type(2)));

// Kernel A: dinv[r] = 1/sqrt(1 + sum_j adj[r][j]); one wave per row.
__global__ __launch_bounds__(64) void dinv_kernel(
    const float* __restrict__ adj, float* __restrict__ dinv) {
    const int r = blockIdx.x;
    const int lane = threadIdx.x;
    float s = (lane == 0) ? 1.0f : 0.0f;   // self-loop +1
    for (int j = lane; j < N_NODES; j += 64) s += adj[r * N_NODES + j];
#pragma unroll
    for (int off = 32; off; off >>= 1) s += __shfl_down(s, off);
    if (lane == 0) dinv[r] = 1.0f / sqrtf(s);
}

// Kernel B: col[i*NPC+k] = dinv[i] * (adj[i][j] + (i==j)) * dinv[j], j=id*NPC+k
__global__ __launch_bounds__(256) void col_kernel(
    const float* __restrict__ adj, const float* __restrict__ dinv,
    const int* __restrict__ idp, float* __restrict__ col) {
    const int idx = blockIdx.x * 256 + threadIdx.x;
    if (idx >= N_NODES * NPC) return;
    const int i = idx / NPC;
    const int k = idx - i * NPC;
    const int j = (*idp) * NPC + k;
    float a = adj[i * N_NODES + j] + (i == j ? 1.0f : 0.0f);
    col[idx] = dinv[i] * a * dinv[j];
}

// Kernel C: out[b][n][d] = sum_k col[n][k] * X[k][b*ODIM+d]
// col is read with wave-uniform addresses -> scalar s_load path (no LDS,
// no VMEM per lane). X held in registers (float2/thread, ~70 VGPR).
__global__ __launch_bounds__(256) void gcn_mm_kernel(
    const float* __restrict__ X, const float* __restrict__ col,
    float* __restrict__ out) {
    const int n0 = blockIdx.y * NCHUNK;
    const int n1 = (n0 + NCHUNK < N_NODES) ? (n0 + NCHUNK) : N_NODES;

    const int j0 = (blockIdx.x * 256 + threadIdx.x) * 2;
    v2f x[NPC];
#pragma unroll
    for (int k = 0; k < NPC; ++k)
        x[k] = *(const v2f*)(X + (size_t)k * ROWLEN + j0);

    const int b = j0 >> 8;          // j0 / ODIM
    const int d = j0 & (ODIM - 1);
    float* obase = out + (size_t)b * (N_NODES * ODIM) + d;

    for (int n = n0; n < n1; ++n) {
        // wave-uniform loads -> s_load_dwordx8 clusters on the scalar pipe
        float c[NPC];
        const float* cn = col + n * NPC;
#pragma unroll
        for (int k = 0; k < NPC; ++k) c[k] = cn[k];

        v2f acc = {0.f, 0.f};
#pragma unroll
        for (int k = 0; k < NPC; ++k) {
            acc.x = fmaf(c[k], x[k].x, acc.x);
            acc.y = fmaf(c[k], x[k].y, acc.y);
        }
        __builtin_nontemporal_store(acc, (v2f*)(obase + (size_t)n * ODIM));
    }
}

extern "C" void kernel_launch(void* const* d_in, const int* in_sizes, int n_in,
                              void* d_out, int out_size, void* d_ws, size_t ws_size,
                              hipStream_t stream) {
    const float* adj = (const float*)d_in[0];   // (203, 203)
    const float* X   = (const float*)d_in[1];   // (29, 524288)
    const int*   idp = (const int*)d_in[4];     // scalar id
    float* out  = (float*)d_out;                // (2048, 203, 256)
    float* dinv = (float*)d_ws;                 // 203 floats
    float* col  = (float*)d_ws + 256;           // 203*29 floats

    dinv_kernel<<<N_NODES, 64, 0, stream>>>(adj, dinv);
    col_kernel<<<(N_NODES * NPC + 255) / 256, 256, 0, stream>>>(adj, dinv, idp, col);

    dim3 grid(ROWLEN / (256 * 2), NSPLIT);      // (1024, 2)
    gcn_mm_kernel<<<grid, 256, 0, stream>>>(X, col, out);
}